// Round 8
// baseline (121.810 us; speedup 1.0000x reference)
//
#include <hip/hip_runtime.h>
#include <hip/hip_bf16.h>
#include <math.h>

#define D_MODEL 512
#define N_HEADS 16
#define HEAD_DIM 32
#define T_SEQ 2048
#define B_SZ 2
#define NTOK (B_SZ * T_SEQ)        // 4096
#define QKV_DIM (3 * D_MODEL)      // 1536

typedef short short8 __attribute__((ext_vector_type(8)));
typedef float f32x4  __attribute__((ext_vector_type(4)));

__device__ __forceinline__ float bf2f(unsigned int u16) {
    union { unsigned int i; float f; } v;
    v.i = u16 << 16;
    return v.f;
}

__device__ __forceinline__ unsigned short f2bf(float f) {   // RNE
    union { float f; unsigned int i; } v;
    v.f = f;
    unsigned int lsb = (v.i >> 16) & 1u;
    v.i += 0x7fffu + lsb;
    return (unsigned short)(v.i >> 16);
}

__device__ __forceinline__ unsigned int f2bf_tru32(float f) {  // bf16 in low 16, f >= 0
    union { float f; unsigned int i; } v;
    v.f = f;
    return v.i >> 16;
}

__device__ __forceinline__ void gld_lds16(const void* g, void* l) {
    __builtin_amdgcn_global_load_lds(
        (const __attribute__((address_space(1))) void*)g,
        (__attribute__((address_space(3))) void*)l, 16, 0, 0);
}

// single fused fp32->bf16 convert for x | w_qkv | w_o (float4 granules)
#define N4_X   (NTOK * D_MODEL / 4)            // 524288
#define N4_WQ  (QKV_DIM * D_MODEL / 4)         // 196608
#define N4_WO  (D_MODEL * D_MODEL / 4)         // 65536
__global__ __launch_bounds__(256) void cvt_all(const float* __restrict__ x,
                                               const float* __restrict__ wq,
                                               const float* __restrict__ wo,
                                               unsigned short* __restrict__ xb,
                                               unsigned short* __restrict__ wqb,
                                               unsigned short* __restrict__ wob) {
    int i = blockIdx.x * 256 + threadIdx.x;
    const float* in;
    unsigned short* out;
    int k;
    if (i < N4_X)                { in = x;  out = xb;  k = i; }
    else if (i < N4_X + N4_WQ)   { in = wq; out = wqb; k = i - N4_X; }
    else if (i < N4_X + N4_WQ + N4_WO) { in = wo; out = wob; k = i - N4_X - N4_WQ; }
    else return;
    float4 v = ((const float4*)in)[k];
    ushort4 o;
    o.x = f2bf(v.x); o.y = f2bf(v.y); o.z = f2bf(v.z); o.w = f2bf(v.w);
    ((ushort4*)out)[k] = o;
}

// ---------------------------------------------------------------------------
// MT x 64 tile MFMA NT-GEMM (verified R0 structure, exact).
// ---------------------------------------------------------------------------
#define LOG2_10000_D16 0.8304820237218405f
#define QSCALE_LOG2 0.2550348788f   // (1/sqrt(32)) * log2(e)

template<int MT, int LDA, int LDC, bool OUT_BF16, bool ROPE>
__global__ __launch_bounds__(256) void gemm_nt(const unsigned short* __restrict__ A,
                                               const unsigned short* __restrict__ B,
                                               void* __restrict__ Cout,
                                               unsigned short* __restrict__ kb,
                                               unsigned short* __restrict__ vt) {
    __shared__ unsigned short Als[MT * 64];
    __shared__ unsigned short Bls[64 * 64];

    const int tid = threadIdx.x;
    const int m0 = blockIdx.y * MT;
    const int n0 = blockIdx.x * 64;

    const int wid  = tid >> 6;
    const int lane = tid & 63;
    const int c    = lane & 15;
    const int quad = lane >> 4;
    const int wm = (wid >> 1) * (MT / 2);
    const int wn = (wid & 1) * 32;
    const int MI = MT / 32;

    f32x4 acc[MI][2];
#pragma unroll
    for (int i = 0; i < MI; ++i)
#pragma unroll
        for (int j = 0; j < 2; ++j) acc[i][j] = (f32x4)0.f;

    const int srow = wid * 8 + (lane >> 3);
    const int schk = lane & 7;

    for (int k0 = 0; k0 < 512; k0 += 64) {
#pragma unroll
        for (int it = 0; it < MT / 32; ++it) {
            const unsigned short* g = A + (size_t)(m0 + it * 32 + srow) * LDA + k0 + schk * 8;
            gld_lds16(g, &Als[(it * 32 + srow) * 64 + schk * 8]);
        }
#pragma unroll
        for (int it = 0; it < 2; ++it) {
            const unsigned short* g = B + (size_t)(n0 + it * 32 + srow) * 512 + k0 + schk * 8;
            gld_lds16(g, &Bls[(it * 32 + srow) * 64 + schk * 8]);
        }
        __syncthreads();

#pragma unroll
        for (int kk = 0; kk < 2; ++kk) {
            short8 af[MI], bfr[2];
#pragma unroll
            for (int i = 0; i < MI; ++i)
                af[i] = *(const short8*)&Als[(wm + i * 16 + c) * 64 + kk * 32 + quad * 8];
#pragma unroll
            for (int j = 0; j < 2; ++j)
                bfr[j] = *(const short8*)&Bls[(wn + j * 16 + c) * 64 + kk * 32 + quad * 8];
#pragma unroll
            for (int i = 0; i < MI; ++i)
#pragma unroll
                for (int j = 0; j < 2; ++j)
                    acc[i][j] = __builtin_amdgcn_mfma_f32_16x16x32_bf16(af[i], bfr[j], acc[i][j], 0, 0, 0);
        }
        __syncthreads();
    }

    if (ROPE) {
        const int sec = n0 >> 9;     // 0 = Q, 1 = K, 2 = V
        if (sec == 0) {
            const float invf = exp2f(-LOG2_10000_D16 * (float)c);
#pragma unroll
            for (int i = 0; i < MI; ++i)
#pragma unroll
                for (int r = 0; r < 4; ++r) {
                    int t = (m0 + wm + i * 16 + quad * 4 + r) & (T_SEQ - 1);
                    float ss, cc;
                    sincosf((float)t * invf, &ss, &cc);
                    float e0 = acc[i][0][r], e1 = acc[i][1][r];
                    acc[i][0][r] = (e0 * cc - e1 * ss) * QSCALE_LOG2;
                    acc[i][1][r] = (e1 * cc + e0 * ss) * QSCALE_LOG2;
                }
            // falls through to generic bf16 writer -> qb (LDC = 512)
        } else if (sec == 1) {
            const float invf = exp2f(-LOG2_10000_D16 * (float)c);
            const int head = ((n0 - 512) + wn) >> 5;
#pragma unroll
            for (int i = 0; i < MI; ++i)
#pragma unroll
                for (int r = 0; r < 4; ++r) {
                    int mm = m0 + wm + i * 16 + quad * 4 + r;
                    int t = mm & (T_SEQ - 1);
                    float ss, cc;
                    sincosf((float)t * invf, &ss, &cc);
                    float e0 = acc[i][0][r], e1 = acc[i][1][r];
                    float k0v = e0 * cc - e1 * ss;     // d = c
                    float k1v = e1 * cc + e0 * ss;     // d = 16 + c
                    int bh = (mm >> 11) * 16 + head;
                    int s = (t & 3) ^ ((t >> 2) & 3);
                    unsigned short* row = kb + ((size_t)(bh * 2048 + t)) * 32;
                    row[((((c) >> 3) ^ s) << 3) + (c & 7)]        = f2bf(k0v);
                    row[((((16 + c) >> 3) ^ s) << 3) + (c & 7)]   = f2bf(k1v);
                }
            return;
        } else {
            // V -> vt[bh][d][t] with chunk swizzle; 4 acc rows = 4 consec t
#pragma unroll
            for (int i = 0; i < MI; ++i)
#pragma unroll
                for (int j = 0; j < 2; ++j) {
                    int nl = n0 - 1024 + wn + j * 16;
                    int head = nl >> 5;
                    int d = (nl & 16) + c;
                    int mm = m0 + wm + i * 16 + quad * 4;
                    int bI = mm >> 11;
                    int pos = mm & (T_SEQ - 1);
                    int phys = ((pos >> 3) & 7) ^ (d & 7);
                    size_t base = ((size_t)((bI * 16 + head) * 32 + d)) * 2048
                                  + (pos & ~63) + (phys << 3) + (pos & 7);
                    ushort4 st;
                    st.x = f2bf(acc[i][j][0]); st.y = f2bf(acc[i][j][1]);
                    st.z = f2bf(acc[i][j][2]); st.w = f2bf(acc[i][j][3]);
                    *(ushort4*)(vt + base) = st;
                }
            return;
        }
    }

    if (OUT_BF16) {
        unsigned short* Cb = (unsigned short*)Cout;
#pragma unroll
        for (int i = 0; i < MI; ++i)
#pragma unroll
            for (int j = 0; j < 2; ++j)
#pragma unroll
                for (int r = 0; r < 4; ++r) {
                    int mm = m0 + wm + i * 16 + quad * 4 + r;
                    int nn = n0 + wn + j * 16 + c;
                    Cb[(size_t)mm * LDC + nn] = f2bf(acc[i][j][r]);
                }
    } else {
        float* Cf = (float*)Cout;
#pragma unroll
        for (int i = 0; i < MI; ++i)
#pragma unroll
            for (int j = 0; j < 2; ++j)
#pragma unroll
                for (int r = 0; r < 4; ++r) {
                    int mm = m0 + wm + i * 16 + quad * 4 + r;
                    int nn = n0 + wn + j * 16 + c;
                    Cf[(size_t)mm * LDC + nn] = acc[i][j][r];
                }
    }
}

// ---------------------------------------------------------------------------
// Flash attention v11: v10's swapped-QK^T/vectorized-P + KVBLK=128.
//  Two 64-key sub-tiles per barrier pair: barrier pairs 16896 -> 8704 and
//  staging sequences halved, at UNCHANGED grid (1024 blocks) — v8's fatter
//  iterations without v8's occupancy loss.
//  Per pair-iteration: stage 2 K + 2 V sub-tiles (reg-prefetched one pair
//  ahead), 8 QK MFMA, 32 exp2, 8 b64 P-writes (rows padded to 136), 8 PV
//  MFMA. Masking: global key vs q compare on the LAST pair (also zeroes the
//  phantom sub-tile when nkt is odd; exp2(-30000) == 0).
//  K/V/P swizzles identical to v10 (sub-tile-local, verified).
// ---------------------------------------------------------------------------
__global__ __launch_bounds__(256) void flash_attn(const unsigned short* __restrict__ qb,
                                                  const unsigned short* __restrict__ kb,
                                                  const unsigned short* __restrict__ vt,
                                                  unsigned short* __restrict__ ob) {
    __shared__ unsigned short KtL[128 * 32];    // [key][32 halves, chunk-swizzled per row]
    __shared__ unsigned short VtL[32 * 128];    // [d][128 halves, chunk-swizzled per 64]
    __shared__ unsigned short Pl[4 * 16 * 136]; // per-wave 16 q-rows x 136 (128 keys + pad)

    const int idx   = blockIdx.x;             // 0..1023
    const int qtile = 31 - (idx >> 5);        // globally heavy first
    const int bh    = idx & 31;
    const int b = bh >> 4, h = bh & 15;
    const int tid  = threadIdx.x;
    const int wid  = tid >> 6;
    const int lane = tid & 63;
    const int c    = lane & 15;
    const int quad = lane >> 4;

    const int q0w = qtile * 64 + wid * 16;
    const int sK = (c & 3) ^ ((c >> 2) & 3);   // K chunk swizzle (key mod 16 = c)
    const int sP = c & 7;                      // V chunk swizzle (d & 7 = c & 7)

    short8 qf = *(const short8*)(qb + ((size_t)(b * T_SEQ + q0w + c)) * 512 + h * HEAD_DIM + quad * 8);

    f32x4 accO[2];
    accO[0] = (f32x4)0.f; accO[1] = (f32x4)0.f;
    float l_part = 0.f;                        // partial denom for q = q0w + c

    unsigned short* plw = &Pl[wid * 16 * 136];

    // staging coordinates (verified gld-compatible lane-contiguous mapping)
    const int krow = tid >> 2, kch = tid & 3;
    const int vd   = tid >> 3, vch = tid & 7;
    const unsigned short* kbase = kb + (size_t)bh * 2048 * 32 + (size_t)krow * 32 + kch * 8;
    const unsigned short* vbase = vt + ((size_t)(bh * 32 + vd)) * 2048 + vch * 8;
    // LDS staging destinations (sub-tile s at +s*64 keys)
    unsigned short* kdst = &KtL[(size_t)krow * 32 + kch * 8];
    unsigned short* vdst = &VtL[(size_t)vd * 128 + vch * 8];

    const int nkt = qtile + 1;                 // 64-key sub-tiles
    const int npairs = (qtile + 2) >> 1;       // 128-key pair iterations

    uint4 kreg0 = *(const uint4*)(kbase);
    uint4 kreg1 = *(const uint4*)(kbase + (size_t)64 * 32);
    uint4 vreg0 = *(const uint4*)(vbase);
    uint4 vreg1 = *(const uint4*)(vbase + 64);

    for (int p = 0; p < npairs; ++p) {
        __syncthreads();                    // prior compute done reading LDS
        *(uint4*)kdst                = kreg0;
        *(uint4*)(kdst + 64 * 32)    = kreg1;
        *(uint4*)vdst                = vreg0;
        *(uint4*)(vdst + 64)         = vreg1;
        __syncthreads();                    // staging visible

        if (p + 1 < npairs) {               // prefetch next pair into regs
            const size_t k0 = (size_t)(p + 1) * 2 * 64 * 32;
            kreg0 = *(const uint4*)(kbase + k0);
            kreg1 = *(const uint4*)(kbase + k0 + 64 * 32);
            vreg0 = *(const uint4*)(vbase + (p + 1) * 128);
            vreg1 = *(const uint4*)(vbase + (p + 1) * 128 + 64);
        }

        // --- S^T = K.Q^T : sv[j][r] = S[key=p*128+j*16+quad*4+r][q=q0w+c] ---
        f32x4 sv[8];
#pragma unroll
        for (int j = 0; j < 8; ++j) {
            short8 kf = *(const short8*)&KtL[(j * 16 + c) * 32 + ((quad ^ sK) << 3)];
            f32x4 z = (f32x4)0.f;
            sv[j] = __builtin_amdgcn_mfma_f32_16x16x32_bf16(kf, qf, z, 0, 0, 0);
        }

        if (p == npairs - 1) {              // causal: mask key > q (covers odd tail)
            const int keyb = p * 128;
#pragma unroll
            for (int j = 0; j < 8; ++j)
#pragma unroll
                for (int r = 0; r < 4; ++r)
                    if (keyb + j * 16 + quad * 4 + r > q0w + c) sv[j][r] = -30000.f;
        }

        // --- static softmax base-2; P -> LDS rows [q][key], b64 writes ---
#pragma unroll
        for (int j = 0; j < 8; ++j) {
            float p0 = exp2f(sv[j][0]);
            float p1 = exp2f(sv[j][1]);
            float p2 = exp2f(sv[j][2]);
            float p3 = exp2f(sv[j][3]);
            l_part += (p0 + p1) + (p2 + p3);
            unsigned int w0 = f2bf_tru32(p0) | (f2bf_tru32(p1) << 16);
            unsigned int w1 = f2bf_tru32(p2) | (f2bf_tru32(p3) << 16);
            uint2 w = make_uint2(w0, w1);
            *(uint2*)&plw[c * 136 + j * 16 + quad * 4] = w;   // ushort idx = key
        }

        // --- PV : A = P[q][k] fragment (row q=c), B = V ---
#pragma unroll
        for (int kk = 0; kk < 4; ++kk) {
            short8 pf = *(const short8*)&plw[c * 136 + kk * 32 + quad * 8];
            const int kc = kk * 4 + quad;                 // key chunk 0..15
            const int voff = ((kc & 8) << 3) + (((kc & 7) ^ sP) << 3);
#pragma unroll
            for (int ns = 0; ns < 2; ++ns) {
                short8 vf = *(const short8*)&VtL[(ns * 16 + c) * 128 + voff];
                accO[ns] = __builtin_amdgcn_mfma_f32_16x16x32_bf16(pf, vf, accO[ns], 0, 0, 0);
            }
        }
    }

    // --- epilogue: l lives per q=c; reduce across quads, redistribute ---
    float lr = l_part;
    lr += __shfl_xor(lr, 16);
    lr += __shfl_xor(lr, 32);               // lane (c,quad) holds l[q0w + c]
#pragma unroll
    for (int r = 0; r < 4; ++r) {
        float lq = __shfl(lr, quad * 4 + r);    // l for q-local = quad*4+r
        float inv = 1.f / lq;
        int qg = q0w + quad * 4 + r;
        unsigned short* op = ob + ((size_t)(b * T_SEQ + qg)) * 512 + h * HEAD_DIM;
#pragma unroll
        for (int ns = 0; ns < 2; ++ns)
            op[ns * 16 + c] = f2bf(accO[ns][r] * inv);
    }
}

extern "C" void kernel_launch(void* const* d_in, const int* in_sizes, int n_in,
                              void* d_out, int out_size, void* d_ws, size_t ws_size,
                              hipStream_t stream) {
    const float* x     = (const float*)d_in[0];
    const float* w_qkv = (const float*)d_in[1];
    const float* w_o   = (const float*)d_in[2];
    float* out = (float*)d_out;

    // workspace (ushorts): qb 4MB | kb 4 | vt 4 | xb 4 | wqb 1.5 | wob 0.5 | ob 4
    unsigned short* qb  = (unsigned short*)d_ws;
    unsigned short* kb  = qb  + (size_t)NTOK * D_MODEL;
    unsigned short* vt  = kb  + (size_t)32 * 2048 * 32;
    unsigned short* xb  = vt  + (size_t)32 * 32 * 2048;
    unsigned short* wqb = xb  + (size_t)NTOK * D_MODEL;
    unsigned short* wob = wqb + (size_t)QKV_DIM * D_MODEL;
    unsigned short* ob  = wob + (size_t)D_MODEL * D_MODEL;

    {
        int total = N4_X + N4_WQ + N4_WO;
        cvt_all<<<(total + 255) / 256, 256, 0, stream>>>(x, w_qkv, w_o, xb, wqb, wob);
    }
    // QKV projection + fused RoPE/scale; Q->qb, K->kb (swizzled), V->vt (swizzled)
    {
        dim3 grid(QKV_DIM / 64, NTOK / 128);   // (24, 32) = 768 blocks
        gemm_nt<128, D_MODEL, D_MODEL, true, true><<<grid, 256, 0, stream>>>(xb, wqb, qb, kb, vt);
    }
    // Flash: 1024 blocks, globally heavy-first, KVBLK=128
    {
        flash_attn<<<1024, 256, 0, stream>>>(qb, kb, vt, ob);
    }
    // Output projection (A = attn in ob, lda 512) -> fp32 out
    {
        dim3 grid(D_MODEL / 64, NTOK / 64);   // (8, 64) = 512 blocks
        gemm_nt<64, D_MODEL, D_MODEL, false, false><<<grid, 256, 0, stream>>>(ob, wob, out, nullptr, nullptr);
    }
}